// Round 5
// baseline (289.996 us; speedup 1.0000x reference)
//
#include <hip/hip_runtime.h>

// BaseAttention: B=2 H=16 S=2048 D=64, fp32 in/out.
// Round 5: round-4 structure (32x32x16 MFMA, S^T=K*Q^T, P in registers,
// swizzled Vt) + two latency fixes:
//   1. K-split x2 across blockIdx.z: no online max -> partials combine by
//      pure addition. Main kernel writes unnormalized O + l to d_ws;
//      a small combine kernel does out = (O0+O1)/(l0+l1).
//      Grid 512 -> 1024 blocks (4 blocks/CU, occupancy 22% -> ~50%).
//   2. Double-buffered LDS: ONE __syncthreads per K-iter (was 2); staging
//      of tile k+1 overlaps compute of tile k.
// Fallback: if ws_size < 34 MB, launch the unsplit single-kernel variant.

#define S_LEN 2048
#define D_DIM 64
#define N_KT 32
#define LDK 72  // shorts per Ks row (144 B -> bank-rotating b128 reads)
#define LDV 72  // shorts per Vt row (+ chunk swizzle)

typedef __attribute__((ext_vector_type(8))) short bf16x8;
typedef __attribute__((ext_vector_type(16))) float f32x16;

#define C1 0.180336880111121f    // 0.125 * log2(e)
#define CM (-14426.9504088896f)  // -10000 * log2(e)

static __device__ __forceinline__ unsigned short f2bf(float f) {
  union { float f; unsigned u; } x; x.f = f;
  return (unsigned short)((x.u + 0x8000u) >> 16);
}
static __device__ __forceinline__ unsigned packbf(float lo, float hi) {
  union { float f; unsigned u; } a, b; a.f = lo; b.f = hi;
  return ((a.u + 0x8000u) >> 16) | ((b.u + 0x8000u) & 0xffff0000u);
}
static __device__ __forceinline__ f32x16 zero16() {
  f32x16 z;
#pragma unroll
  for (int i = 0; i < 16; ++i) z[i] = 0.f;
  return z;
}

template <int NSPLIT>
__global__ __launch_bounds__(256, 4) void attn_fwd(
    const float* __restrict__ q, const float* __restrict__ k,
    const float* __restrict__ v, const int* __restrict__ mask,
    float* __restrict__ outp,    // NSPLIT==1: final out; else partial O
    float* __restrict__ lpart) { // NSPLIT>1: partial l
  const int qt = blockIdx.x;  // 0..15 (128 q rows per block)
  const int bh = blockIdx.y;  // 0..31
  const int kh = (NSPLIT > 1) ? blockIdx.z : 0;
  const int NT = N_KT / NSPLIT;
  const int kt0 = kh * NT;
  const size_t hoff = (size_t)bh * (S_LEN * D_DIM);

  __shared__ unsigned short Ks[2][64 * LDK];  // Ks[buf][key][d]
  __shared__ unsigned short Vt[2][64 * LDV];  // Vt[buf][d][j], chunk-swizzled

  const int t = threadIdx.x;
  const int wave = t >> 6;
  const int lane = t & 63;
  const int col = lane & 31;  // MFMA m/n index; this lane's q row (mod 32)
  const int hl = lane >> 5;   // half-wave
  const int sw = col >> 2;    // Vt swizzle rotation for fragment reads

  const int qg = qt * 128 + wave * 32 + col;  // this lane's q row within head

  // ---- Q^T B-fragments, straight from global (no LDS): B[k=d][n=q] ----
  bf16x8 bQ[4];
  {
    const float* qrow = q + hoff + (size_t)qg * D_DIM;
#pragma unroll
    for (int ks = 0; ks < 4; ++ks) {
      const float4 x0 = *(const float4*)(qrow + ks * 16 + hl * 8);
      const float4 x1 = *(const float4*)(qrow + ks * 16 + hl * 8 + 4);
      union { bf16x8 v; unsigned d[4]; } u;
      u.d[0] = packbf(x0.x, x0.y);
      u.d[1] = packbf(x0.z, x0.w);
      u.d[2] = packbf(x1.x, x1.y);
      u.d[3] = packbf(x1.z, x1.w);
      bQ[ks] = u.v;
    }
  }

  // ---- prefetch first K/V tile ----
  float4 pk[4], pv[4];
  {
    const float4* kg = (const float4*)(k + hoff + (size_t)kt0 * 64 * D_DIM);
    const float4* vg = (const float4*)(v + hoff + (size_t)kt0 * 64 * D_DIM);
#pragma unroll
    for (int j = 0; j < 4; ++j) {
      pk[j] = kg[t + j * 256];
      pv[j] = vg[t + j * 256];
    }
  }

  f32x16 oT0 = zero16(), oT1 = zero16();  // O^T, d-blocks 0/1, col = q
  float lacc = 0.f;

  const int* mrow = mask + (size_t)qg * S_LEN;

  for (int kt = kt0; kt < kt0 + NT; ++kt) {
    unsigned short* Ksb = Ks[kt & 1];
    unsigned short* Vtb = Vt[kt & 1];
    // ---- stage K (row-major) + V (transposed, swizzled) as bf16 ----
    // Safe without a leading barrier: the previous iteration's barrier
    // guarantees all waves finished compute on this buffer (double buffer).
#pragma unroll
    for (int j = 0; j < 4; ++j) {
      const int i = t + j * 256;
      const int row = i >> 4, c4 = i & 15;
      ushort4 w;
      w.x = f2bf(pk[j].x); w.y = f2bf(pk[j].y);
      w.z = f2bf(pk[j].z); w.w = f2bf(pk[j].w);
      *(ushort4*)&Ksb[row * LDK + c4 * 4] = w;
      const int swc = 8 * (((row >> 3) + c4) & 7) + (row & 7);
      Vtb[(4 * c4 + 0) * LDV + swc] = f2bf(pv[j].x);
      Vtb[(4 * c4 + 1) * LDV + swc] = f2bf(pv[j].y);
      Vtb[(4 * c4 + 2) * LDV + swc] = f2bf(pv[j].z);
      Vtb[(4 * c4 + 3) * LDV + swc] = f2bf(pv[j].w);
    }

    // ---- issue next tile's global loads (consumed next iteration) ----
    if (kt + 1 < kt0 + NT) {
      const float4* kg = (const float4*)(k + hoff + (size_t)(kt + 1) * 64 * D_DIM);
      const float4* vg = (const float4*)(v + hoff + (size_t)(kt + 1) * 64 * D_DIM);
#pragma unroll
      for (int j = 0; j < 4; ++j) {
        pk[j] = kg[t + j * 256];
        pv[j] = vg[t + j * 256];
      }
    }

    __syncthreads();  // staging of buf[kt&1] visible; one barrier per iter

    // ---- mask loads early (hide latency under MFMAs) ----
    int4 mq[2][4];
#pragma unroll
    for (int kb = 0; kb < 2; ++kb)
#pragma unroll
      for (int g = 0; g < 4; ++g)
        mq[kb][g] = *(const int4*)(mrow + kt * 64 + kb * 32 + g * 8 + hl * 4);

    // ---- S^T = K Q^T : 2 key-blocks x 4 k-steps (k = d) ----
    f32x16 sT0 = zero16(), sT1 = zero16();
#pragma unroll
    for (int ks = 0; ks < 4; ++ks) {
      const bf16x8 aK0 = *(const bf16x8*)&Ksb[(col) * LDK + ks * 16 + hl * 8];
      const bf16x8 aK1 = *(const bf16x8*)&Ksb[(32 + col) * LDK + ks * 16 + hl * 8];
      sT0 = __builtin_amdgcn_mfma_f32_32x32x16_bf16(aK0, bQ[ks], sT0, 0, 0, 0);
      sT1 = __builtin_amdgcn_mfma_f32_32x32x16_bf16(aK1, bQ[ks], sT1, 0, 0, 0);
    }

    // ---- p = exp2(s*C1 + mask*CM) in S^T C-layout; pack bf16 pairs ----
    unsigned pw[2][8];
#pragma unroll
    for (int kb = 0; kb < 2; ++kb) {
      const f32x16 sT = kb ? sT1 : sT0;
      float e[16];
#pragma unroll
      for (int g = 0; g < 4; ++g) {
        const int4 mv = mq[kb][g];
        const int* mvp = &mv.x;
#pragma unroll
        for (int r3 = 0; r3 < 4; ++r3) {
          const int reg = g * 4 + r3;
          const float bias = mvp[r3] ? CM : 0.0f;
          const float ev = __builtin_amdgcn_exp2f(fmaf(sT[reg], C1, bias));
          e[reg] = ev;
          lacc += ev;
        }
        pw[kb][g * 2 + 0] = packbf(e[g * 4 + 0], e[g * 4 + 1]);
        pw[kb][g * 2 + 1] = packbf(e[g * 4 + 2], e[g * 4 + 3]);
      }
    }

    // ---- O^T += Vt * P^T : P^T B-frags via half-wave exchange ----
#pragma unroll
    for (int ks = 0; ks < 4; ++ks) {
      const int kb = ks >> 1, h = ks & 1;
      const unsigned d0 = pw[kb][4 * h + 0], d1 = pw[kb][4 * h + 1];
      const unsigned d2 = pw[kb][4 * h + 2], d3 = pw[kb][4 * h + 3];
      const unsigned s0 = hl ? d0 : d2;
      const unsigned s1 = hl ? d1 : d3;
      const unsigned r0 = (unsigned)__shfl_xor((int)s0, 32);
      const unsigned r1 = (unsigned)__shfl_xor((int)s1, 32);
      union { bf16x8 v; unsigned d[4]; } pf;
      pf.d[0] = hl ? r0 : d0;
      pf.d[1] = hl ? r1 : d1;
      pf.d[2] = hl ? d2 : r0;
      pf.d[3] = hl ? d3 : r1;
      const int cpr = 8 * (((2 * ks + hl) + sw) & 7);
      const bf16x8 aV0 = *(const bf16x8*)&Vtb[(col) * LDV + cpr];
      const bf16x8 aV1 = *(const bf16x8*)&Vtb[(32 + col) * LDV + cpr];
      oT0 = __builtin_amdgcn_mfma_f32_32x32x16_bf16(aV0, pf.v, oT0, 0, 0, 0);
      oT1 = __builtin_amdgcn_mfma_f32_32x32x16_bf16(aV1, pf.v, oT1, 0, 0, 0);
    }
  }

  // ---- epilogue ----
  const float ltot = lacc + __shfl_xor(lacc, 32);
  if (NSPLIT == 1) {
    const float inv = 1.0f / ltot;
    float* orow = outp + hoff + (size_t)qg * D_DIM;
#pragma unroll
    for (int rg = 0; rg < 4; ++rg) {
      float4 w0, w1;
      w0.x = oT0[rg * 4 + 0] * inv; w0.y = oT0[rg * 4 + 1] * inv;
      w0.z = oT0[rg * 4 + 2] * inv; w0.w = oT0[rg * 4 + 3] * inv;
      w1.x = oT1[rg * 4 + 0] * inv; w1.y = oT1[rg * 4 + 1] * inv;
      w1.z = oT1[rg * 4 + 2] * inv; w1.w = oT1[rg * 4 + 3] * inv;
      *(float4*)(orow + 8 * rg + 4 * hl) = w0;
      *(float4*)(orow + 32 + 8 * rg + 4 * hl) = w1;
    }
  } else {
    const size_t prow = (size_t)(kh * 32 + bh) * S_LEN + qg;
    float* orow = outp + prow * D_DIM;
#pragma unroll
    for (int rg = 0; rg < 4; ++rg) {
      float4 w0, w1;
      w0.x = oT0[rg * 4 + 0]; w0.y = oT0[rg * 4 + 1];
      w0.z = oT0[rg * 4 + 2]; w0.w = oT0[rg * 4 + 3];
      w1.x = oT1[rg * 4 + 0]; w1.y = oT1[rg * 4 + 1];
      w1.z = oT1[rg * 4 + 2]; w1.w = oT1[rg * 4 + 3];
      *(float4*)(orow + 8 * rg + 4 * hl) = w0;
      *(float4*)(orow + 32 + 8 * rg + 4 * hl) = w1;
    }
    if (hl == 0) lpart[prow] = ltot;
  }
}

// out = (O0 + O1) / (l0 + l1); one thread per 4 output floats.
__global__ __launch_bounds__(256) void attn_combine(
    const float* __restrict__ part, const float* __restrict__ lpart,
    float* __restrict__ out) {
  const int idx = blockIdx.x * 256 + threadIdx.x;
  const int row = idx >> 4;  // bh*S + qrow
  const int c4 = idx & 15;
  const size_t half = (size_t)32 * S_LEN * D_DIM;
  const size_t off = (size_t)row * D_DIM + c4 * 4;
  const float4 a = *(const float4*)(part + off);
  const float4 b = *(const float4*)(part + half + off);
  const float inv = 1.0f / (lpart[row] + lpart[32 * S_LEN + row]);
  float4 w;
  w.x = (a.x + b.x) * inv;
  w.y = (a.y + b.y) * inv;
  w.z = (a.z + b.z) * inv;
  w.w = (a.w + b.w) * inv;
  *(float4*)(out + off) = w;
}

extern "C" void kernel_launch(void* const* d_in, const int* in_sizes, int n_in,
                              void* d_out, int out_size, void* d_ws, size_t ws_size,
                              hipStream_t stream) {
  const float* q = (const float*)d_in[0];
  const float* k = (const float*)d_in[1];
  const float* v = (const float*)d_in[2];
  const int* mask = (const int*)d_in[3];
  float* out = (float*)d_out;

  const size_t o_elems = (size_t)2 * 32 * S_LEN * D_DIM;   // 8.4M floats
  const size_t l_elems = (size_t)2 * 32 * S_LEN;           // 131K floats
  const size_t need = (o_elems + l_elems) * sizeof(float); // ~34 MB

  if (ws_size >= need) {
    float* part = (float*)d_ws;
    float* lpart = part + o_elems;
    dim3 grid(S_LEN / 128, 32, 2);
    attn_fwd<2><<<grid, dim3(256), 0, stream>>>(q, k, v, mask, part, lpart);
    const int nthread = 32 * S_LEN * (D_DIM / 4);  // 1,048,576
    attn_combine<<<nthread / 256, 256, 0, stream>>>(part, lpart, out);
  } else {
    dim3 grid(S_LEN / 128, 32, 1);
    attn_fwd<1><<<grid, dim3(256), 0, stream>>>(q, k, v, mask, out, nullptr);
  }
}

// Round 6
// 174.028 us; speedup vs baseline: 1.6664x; 1.6664x over previous
//
#include <hip/hip_runtime.h>

// BaseAttention: B=2 H=16 S=2048 D=64, fp32 in/out.
// Round 6: precompute + DMA staging.
//   prep_kv:   K -> bf16 tile images (LDS byte layout, stride-72 rows);
//              V -> bf16 transposed+chunk-swizzled tile images.
//   prep_mask: mask int32 -> 1 bit/key (u64 per (row, 64-key tile)) via ballot.
//   attn_fwd:  128 threads (2 waves, 64 q rows/block), grid 32x32 = 1024
//              blocks (4/CU). K/V tiles staged by global_load_lds width=16
//              (no VALU, no ds_write issue), double-buffered, 1 barrier/iter.
//              S^T = K Q^T (32x32x16 MFMA), exp2 with bitmask bias, P kept
//              in registers via half-wave shfl, O^T = Vt P^T.
// Round-5 lesson: split-K's 67 MB partial traffic made it memory-bound —
// reverted. Round-4 lesson: in-loop f2bf staging + mask loads were the
// VALU bound — moved to pre-pass.

#define S_LEN 2048
#define D_DIM 64
#define N_KT 32
#define LDK 72
#define LDV 72
#define TILE_SHORTS (64 * 72)           // 4608
#define TILE_BYTES (TILE_SHORTS * 2)    // 9216
#define NBH 32

typedef __attribute__((ext_vector_type(8))) short bf16x8;
typedef __attribute__((ext_vector_type(16))) float f32x16;
typedef unsigned int u32;
typedef unsigned long long u64;

#define C1 0.180336880111121f    // 0.125 * log2(e)
#define CM (-14426.9504088896f)  // -10000 * log2(e)

static __device__ __forceinline__ unsigned short f2bf(float f) {
  union { float f; unsigned u; } x; x.f = f;
  return (unsigned short)((x.u + 0x8000u) >> 16);
}
static __device__ __forceinline__ unsigned packbf(float lo, float hi) {
  union { float f; unsigned u; } a, b; a.f = lo; b.f = hi;
  return ((a.u + 0x8000u) >> 16) | ((b.u + 0x8000u) & 0xffff0000u);
}
static __device__ __forceinline__ f32x16 zero16() {
  f32x16 z;
#pragma unroll
  for (int i = 0; i < 16; ++i) z[i] = 0.f;
  return z;
}
static __device__ __forceinline__ void dma16(const u32* g, u32* l) {
  __builtin_amdgcn_global_load_lds(
      (const __attribute__((address_space(1))) u32*)g,
      (__attribute__((address_space(3))) u32*)l, 16, 0, 0);
}

// ---- pre-pass: K/V fp32 -> bf16 tile images in workspace ----
__global__ __launch_bounds__(256) void prep_kv(
    const float* __restrict__ k, const float* __restrict__ v,
    unsigned short* __restrict__ kws, unsigned short* __restrict__ vws) {
  const int kt = blockIdx.x, bh = blockIdx.y;
  const int t = threadIdx.x;
  __shared__ unsigned short Vt[TILE_SHORTS];
  const size_t goff = (size_t)bh * (S_LEN * D_DIM) + (size_t)kt * 64 * D_DIM;
  const float4* kg = (const float4*)(k + goff);
  const float4* vg = (const float4*)(v + goff);
  unsigned short* kimg = kws + (size_t)(bh * N_KT + kt) * TILE_SHORTS;
#pragma unroll
  for (int j = 0; j < 4; ++j) {
    const int i = t + j * 256;
    const int row = i >> 4, c4 = i & 15;  // row = key, c4 = d-group
    const float4 x = kg[i];
    ushort4 w;
    w.x = f2bf(x.x); w.y = f2bf(x.y); w.z = f2bf(x.z); w.w = f2bf(x.w);
    *(ushort4*)&kimg[row * LDK + c4 * 4] = w;
    const float4 y = vg[i];
    const int swc = 8 * (((row >> 3) + c4) & 7) + (row & 7);
    Vt[(4 * c4 + 0) * LDV + swc] = f2bf(y.x);
    Vt[(4 * c4 + 1) * LDV + swc] = f2bf(y.y);
    Vt[(4 * c4 + 2) * LDV + swc] = f2bf(y.z);
    Vt[(4 * c4 + 3) * LDV + swc] = f2bf(y.w);
  }
  __syncthreads();
  uint4* vimg = (uint4*)(vws + (size_t)(bh * N_KT + kt) * TILE_SHORTS);
  const uint4* lv = (const uint4*)Vt;
  for (int i = t; i < TILE_BYTES / 16; i += 256) vimg[i] = lv[i];
}

// ---- pre-pass: mask -> bit-per-key, u64 per (row, 64-key tile) ----
__global__ __launch_bounds__(256) void prep_mask(
    const int* __restrict__ mask, u64* __restrict__ mb) {
  const int pair = blockIdx.x * 4 + (threadIdx.x >> 6);  // row*32 + kt
  const int lane = threadIdx.x & 63;
  const int row = pair >> 5, kt = pair & 31;
  const int mv = mask[(size_t)row * S_LEN + kt * 64 + lane];
  const u64 b = __ballot(mv != 0);
  if (lane == 0) mb[pair] = b;
}

// ---- main: flash attention, DMA-staged bf16 tiles ----
__global__ __launch_bounds__(128, 2) void attn_fwd(
    const float* __restrict__ q, const unsigned short* __restrict__ kws,
    const unsigned short* __restrict__ vws, const u64* __restrict__ mb,
    float* __restrict__ out) {
  const int qt = blockIdx.x;  // 0..31 (64 q rows per block)
  const int bh = blockIdx.y;  // 0..31
  const size_t hoff = (size_t)bh * (S_LEN * D_DIM);

  __shared__ unsigned short Ks[2][TILE_SHORTS];
  __shared__ unsigned short Vt[2][TILE_SHORTS];

  const int t = threadIdx.x;
  const int wave = t >> 6;
  const int lane = t & 63;
  const int col = lane & 31;
  const int hl = lane >> 5;
  const int sw = col >> 2;

  const int qg = qt * 64 + wave * 32 + col;  // this lane's q row within head

  // Q^T B-fragments straight from global: B[k=d][n=q]
  bf16x8 bQ[4];
  {
    const float* qrow = q + hoff + (size_t)qg * D_DIM;
#pragma unroll
    for (int ks = 0; ks < 4; ++ks) {
      const float4 x0 = *(const float4*)(qrow + ks * 16 + hl * 8);
      const float4 x1 = *(const float4*)(qrow + ks * 16 + hl * 8 + 4);
      union { bf16x8 v; unsigned d[4]; } u;
      u.d[0] = packbf(x0.x, x0.y);
      u.d[1] = packbf(x0.z, x0.w);
      u.d[2] = packbf(x1.x, x1.y);
      u.d[3] = packbf(x1.z, x1.w);
      bQ[ks] = u.v;
    }
  }

  const unsigned short* kbase = kws + (size_t)bh * N_KT * TILE_SHORTS;
  const unsigned short* vbase = vws + (size_t)bh * N_KT * TILE_SHORTS;

  f32x16 oT0 = zero16(), oT1 = zero16();
  float lacc = 0.f;
  const u64* mrow = mb + (size_t)qg * N_KT;

  // stage tile 0 into buf 0 (wave 0: K, wave 1: V)
  {
    const u32* g = (const u32*)((wave == 0 ? kbase : vbase));
    u32* l = wave == 0 ? (u32*)&Ks[0][0] : (u32*)&Vt[0][0];
#pragma unroll
    for (int i = 0; i < 9; ++i) dma16(g + i * 256 + lane * 4, l + i * 256);
  }

  for (int kt = 0; kt < N_KT; ++kt) {
    __syncthreads();  // drains DMA for tile kt; orders buffer reuse
    if (kt + 1 < N_KT) {
      const u32* g = (const u32*)((wave == 0 ? kbase : vbase) +
                                  (size_t)(kt + 1) * TILE_SHORTS);
      u32* l = wave == 0 ? (u32*)&Ks[(kt + 1) & 1][0]
                         : (u32*)&Vt[(kt + 1) & 1][0];
#pragma unroll
      for (int i = 0; i < 9; ++i) dma16(g + i * 256 + lane * 4, l + i * 256);
    }
    const u64 mw = mrow[kt];
    const unsigned short* Ksb = Ks[kt & 1];
    const unsigned short* Vtb = Vt[kt & 1];

    // S^T = K Q^T : 2 key-blocks x 4 k-steps
    f32x16 sT0 = zero16(), sT1 = zero16();
#pragma unroll
    for (int ks = 0; ks < 4; ++ks) {
      const bf16x8 aK0 = *(const bf16x8*)&Ksb[col * LDK + ks * 16 + hl * 8];
      const bf16x8 aK1 = *(const bf16x8*)&Ksb[(32 + col) * LDK + ks * 16 + hl * 8];
      sT0 = __builtin_amdgcn_mfma_f32_32x32x16_bf16(aK0, bQ[ks], sT0, 0, 0, 0);
      sT1 = __builtin_amdgcn_mfma_f32_32x32x16_bf16(aK1, bQ[ks], sT1, 0, 0, 0);
    }

    // p = exp2(s*C1 + bit*CM); bit jloc = r3 + 8*g + 4*hl (+32 for kb=1)
    unsigned pw[2][8];
#pragma unroll
    for (int kb = 0; kb < 2; ++kb) {
      const unsigned w = kb ? (unsigned)(mw >> 32) : (unsigned)mw;
      const f32x16 sT = kb ? sT1 : sT0;
      float e[16];
#pragma unroll
      for (int g = 0; g < 4; ++g) {
        const unsigned nib = (w >> (8 * g + 4 * hl)) & 0xFu;
#pragma unroll
        for (int r3 = 0; r3 < 4; ++r3) {
          const int reg = g * 4 + r3;
          const float bias = (nib & (1u << r3)) ? CM : 0.0f;
          const float ev = __builtin_amdgcn_exp2f(fmaf(sT[reg], C1, bias));
          e[reg] = ev;
          lacc += ev;
        }
        pw[kb][g * 2 + 0] = packbf(e[g * 4 + 0], e[g * 4 + 1]);
        pw[kb][g * 2 + 1] = packbf(e[g * 4 + 2], e[g * 4 + 3]);
      }
    }

    // O^T += Vt * P^T : P^T B-frags via half-wave exchange
#pragma unroll
    for (int ks = 0; ks < 4; ++ks) {
      const int kb = ks >> 1, h = ks & 1;
      const unsigned d0 = pw[kb][4 * h + 0], d1 = pw[kb][4 * h + 1];
      const unsigned d2 = pw[kb][4 * h + 2], d3 = pw[kb][4 * h + 3];
      const unsigned s0 = hl ? d0 : d2;
      const unsigned s1 = hl ? d1 : d3;
      const unsigned r0 = (unsigned)__shfl_xor((int)s0, 32);
      const unsigned r1 = (unsigned)__shfl_xor((int)s1, 32);
      union { bf16x8 v; unsigned d[4]; } pf;
      pf.d[0] = hl ? r0 : d0;
      pf.d[1] = hl ? r1 : d1;
      pf.d[2] = hl ? d2 : r0;
      pf.d[3] = hl ? d3 : r1;
      const int cpr = 8 * (((2 * ks + hl) + sw) & 7);
      const bf16x8 aV0 = *(const bf16x8*)&Vtb[col * LDV + cpr];
      const bf16x8 aV1 = *(const bf16x8*)&Vtb[(32 + col) * LDV + cpr];
      oT0 = __builtin_amdgcn_mfma_f32_32x32x16_bf16(aV0, pf.v, oT0, 0, 0, 0);
      oT1 = __builtin_amdgcn_mfma_f32_32x32x16_bf16(aV1, pf.v, oT1, 0, 0, 0);
    }
  }

  const float ltot = lacc + __shfl_xor(lacc, 32);
  const float inv = 1.0f / ltot;
  float* orow = out + hoff + (size_t)qg * D_DIM;
#pragma unroll
  for (int rg = 0; rg < 4; ++rg) {
    float4 w0, w1;
    w0.x = oT0[rg * 4 + 0] * inv; w0.y = oT0[rg * 4 + 1] * inv;
    w0.z = oT0[rg * 4 + 2] * inv; w0.w = oT0[rg * 4 + 3] * inv;
    w1.x = oT1[rg * 4 + 0] * inv; w1.y = oT1[rg * 4 + 1] * inv;
    w1.z = oT1[rg * 4 + 2] * inv; w1.w = oT1[rg * 4 + 3] * inv;
    *(float4*)(orow + 8 * rg + 4 * hl) = w0;
    *(float4*)(orow + 32 + 8 * rg + 4 * hl) = w1;
  }
}

// ---- fallback (round-4 kernel, self-staging) if ws is too small ----
__global__ __launch_bounds__(256, 2) void attn_fwd_self(
    const float* __restrict__ q, const float* __restrict__ k,
    const float* __restrict__ v, const int* __restrict__ mask,
    float* __restrict__ out) {
  const int qt = blockIdx.x;
  const int bh = blockIdx.y;
  const size_t hoff = (size_t)bh * (S_LEN * D_DIM);
  __shared__ unsigned short Ks[64 * LDK];
  __shared__ unsigned short Vt[64 * LDV];
  const int t = threadIdx.x;
  const int wave = t >> 6;
  const int lane = t & 63;
  const int col = lane & 31;
  const int hl = lane >> 5;
  const int sw = col >> 2;
  const int qg = qt * 128 + wave * 32 + col;
  bf16x8 bQ[4];
  {
    const float* qrow = q + hoff + (size_t)qg * D_DIM;
#pragma unroll
    for (int ks = 0; ks < 4; ++ks) {
      const float4 x0 = *(const float4*)(qrow + ks * 16 + hl * 8);
      const float4 x1 = *(const float4*)(qrow + ks * 16 + hl * 8 + 4);
      union { bf16x8 v; unsigned d[4]; } u;
      u.d[0] = packbf(x0.x, x0.y);
      u.d[1] = packbf(x0.z, x0.w);
      u.d[2] = packbf(x1.x, x1.y);
      u.d[3] = packbf(x1.z, x1.w);
      bQ[ks] = u.v;
    }
  }
  float4 pk[4], pv[4];
  {
    const float4* kg = (const float4*)(k + hoff);
    const float4* vg = (const float4*)(v + hoff);
#pragma unroll
    for (int j = 0; j < 4; ++j) { pk[j] = kg[t + j * 256]; pv[j] = vg[t + j * 256]; }
  }
  f32x16 oT0 = zero16(), oT1 = zero16();
  float lacc = 0.f;
  const int* mrow = mask + (size_t)qg * S_LEN;
  for (int kt = 0; kt < N_KT; ++kt) {
    __syncthreads();
#pragma unroll
    for (int j = 0; j < 4; ++j) {
      const int i = t + j * 256;
      const int row = i >> 4, c4 = i & 15;
      ushort4 w;
      w.x = f2bf(pk[j].x); w.y = f2bf(pk[j].y);
      w.z = f2bf(pk[j].z); w.w = f2bf(pk[j].w);
      *(ushort4*)&Ks[row * LDK + c4 * 4] = w;
      const int swc = 8 * (((row >> 3) + c4) & 7) + (row & 7);
      Vt[(4 * c4 + 0) * LDV + swc] = f2bf(pv[j].x);
      Vt[(4 * c4 + 1) * LDV + swc] = f2bf(pv[j].y);
      Vt[(4 * c4 + 2) * LDV + swc] = f2bf(pv[j].z);
      Vt[(4 * c4 + 3) * LDV + swc] = f2bf(pv[j].w);
    }
    __syncthreads();
    if (kt + 1 < N_KT) {
      const float4* kg = (const float4*)(k + hoff + (size_t)(kt + 1) * 64 * D_DIM);
      const float4* vg = (const float4*)(v + hoff + (size_t)(kt + 1) * 64 * D_DIM);
#pragma unroll
      for (int j = 0; j < 4; ++j) { pk[j] = kg[t + j * 256]; pv[j] = vg[t + j * 256]; }
    }
    int4 mq[2][4];
#pragma unroll
    for (int kb = 0; kb < 2; ++kb)
#pragma unroll
      for (int g = 0; g < 4; ++g)
        mq[kb][g] = *(const int4*)(mrow + kt * 64 + kb * 32 + g * 8 + hl * 4);
    f32x16 sT0 = zero16(), sT1 = zero16();
#pragma unroll
    for (int ks = 0; ks < 4; ++ks) {
      const bf16x8 aK0 = *(const bf16x8*)&Ks[col * LDK + ks * 16 + hl * 8];
      const bf16x8 aK1 = *(const bf16x8*)&Ks[(32 + col) * LDK + ks * 16 + hl * 8];
      sT0 = __builtin_amdgcn_mfma_f32_32x32x16_bf16(aK0, bQ[ks], sT0, 0, 0, 0);
      sT1 = __builtin_amdgcn_mfma_f32_32x32x16_bf16(aK1, bQ[ks], sT1, 0, 0, 0);
    }
    unsigned pw[2][8];
#pragma unroll
    for (int kb = 0; kb < 2; ++kb) {
      const f32x16 sT = kb ? sT1 : sT0;
      float e[16];
#pragma unroll
      for (int g = 0; g < 4; ++g) {
        const int4 mv = mq[kb][g];
        const int* mvp = &mv.x;
#pragma unroll
        for (int r3 = 0; r3 < 4; ++r3) {
          const int reg = g * 4 + r3;
          const float bias = mvp[r3] ? CM : 0.0f;
          const float ev = __builtin_amdgcn_exp2f(fmaf(sT[reg], C1, bias));
          e[reg] = ev;
          lacc += ev;
        }
        pw[kb][g * 2 + 0] = packbf(e[g * 4 + 0], e[g * 4 + 1]);
        pw[kb][g * 2 + 1] = packbf(e[g * 4 + 2], e[g * 4 + 3]);
      }
    }
#pragma unroll
    for (int ks = 0; ks < 4; ++ks) {
      const int kb = ks >> 1, h = ks & 1;
      const unsigned d0 = pw[kb][4 * h + 0], d1 = pw[kb][4 * h + 1];
      const unsigned d2 = pw[kb][4 * h + 2], d3 = pw[kb][4 * h + 3];
      const unsigned s0 = hl ? d0 : d2;
      const unsigned s1 = hl ? d1 : d3;
      const unsigned r0 = (unsigned)__shfl_xor((int)s0, 32);
      const unsigned r1 = (unsigned)__shfl_xor((int)s1, 32);
      union { bf16x8 v; unsigned d[4]; } pf;
      pf.d[0] = hl ? r0 : d0;
      pf.d[1] = hl ? r1 : d1;
      pf.d[2] = hl ? d2 : r0;
      pf.d[3] = hl ? d3 : r1;
      const int cpr = 8 * (((2 * ks + hl) + sw) & 7);
      const bf16x8 aV0 = *(const bf16x8*)&Vt[col * LDV + cpr];
      const bf16x8 aV1 = *(const bf16x8*)&Vt[(32 + col) * LDV + cpr];
      oT0 = __builtin_amdgcn_mfma_f32_32x32x16_bf16(aV0, pf.v, oT0, 0, 0, 0);
      oT1 = __builtin_amdgcn_mfma_f32_32x32x16_bf16(aV1, pf.v, oT1, 0, 0, 0);
    }
  }
  const float ltot = lacc + __shfl_xor(lacc, 32);
  const float inv = 1.0f / ltot;
  float* orow = out + hoff + (size_t)qg * D_DIM;
#pragma unroll
  for (int rg = 0; rg < 4; ++rg) {
    float4 w0, w1;
    w0.x = oT0[rg * 4 + 0] * inv; w0.y = oT0[rg * 4 + 1] * inv;
    w0.z = oT0[rg * 4 + 2] * inv; w0.w = oT0[rg * 4 + 3] * inv;
    w1.x = oT1[rg * 4 + 0] * inv; w1.y = oT1[rg * 4 + 1] * inv;
    w1.z = oT1[rg * 4 + 2] * inv; w1.w = oT1[rg * 4 + 3] * inv;
    *(float4*)(orow + 8 * rg + 4 * hl) = w0;
    *(float4*)(orow + 32 + 8 * rg + 4 * hl) = w1;
  }
}

extern "C" void kernel_launch(void* const* d_in, const int* in_sizes, int n_in,
                              void* d_out, int out_size, void* d_ws, size_t ws_size,
                              hipStream_t stream) {
  const float* q = (const float*)d_in[0];
  const float* k = (const float*)d_in[1];
  const float* v = (const float*)d_in[2];
  const int* mask = (const int*)d_in[3];
  float* out = (float*)d_out;

  const size_t img_elems = (size_t)NBH * N_KT * TILE_SHORTS;  // shorts
  const size_t mb_words = (size_t)S_LEN * N_KT;               // u64 count
  const size_t need = img_elems * 2 * sizeof(unsigned short) + mb_words * 8;

  if (ws_size >= need) {
    unsigned short* kws = (unsigned short*)d_ws;
    unsigned short* vws = kws + img_elems;
    u64* mbp = (u64*)(vws + img_elems);
    prep_kv<<<dim3(N_KT, NBH), dim3(256), 0, stream>>>(k, v, kws, vws);
    prep_mask<<<dim3((S_LEN * N_KT) / 4), dim3(256), 0, stream>>>(mask, mbp);
    attn_fwd<<<dim3(S_LEN / 64, NBH), dim3(128), 0, stream>>>(q, kws, vws, mbp, out);
  } else {
    attn_fwd_self<<<dim3(S_LEN / 128, NBH), dim3(256), 0, stream>>>(q, k, v, mask, out);
  }
}

// Round 8
// 169.833 us; speedup vs baseline: 1.7075x; 1.0247x over previous
//
#include <hip/hip_runtime.h>

// BaseAttention: B=2 H=16 S=2048 D=64, fp32 in/out.
// Round 8 (= round 7 + compile fix): VALU diet on the round-6 structure.
//   - Q pre-scaled by 0.125*log2e at fragment build -> MFMA emits scores
//     ready for exp2 (no per-score fma).
//   - mask precomputed as u32 AND-words (0xFFFF/0 per f16 slot) in the exact
//     per-lane pair layout; in-loop masking = 16 v_and per iter.
//   - P packed with v_cvt_pkrtz_f16_f32 (1 op / 2 scores); P,V in f16
//     (more mantissa than bf16); PV = mfma_f32_32x32x16_f16.
//   - l computed by 4 extra ones-A MFMAs on the masked P (exact fp32),
//     no per-score adds.
//   K/V tiles DMA-staged (global_load_lds w16) from prepacked images,
//   double-buffered, 1 barrier/iter. S^T=K Q^T keeps P in registers
//   (half-wave shfl). Round-5 lesson: no split-K (partial-O traffic).

#define S_LEN 2048
#define D_DIM 64
#define N_KT 32
#define LDK 72
#define LDV 72
#define TILE_SHORTS (64 * 72)           // 4608
#define TILE_BYTES (TILE_SHORTS * 2)    // 9216
#define NBH 32

typedef __attribute__((ext_vector_type(8))) short bf16x8;
typedef __attribute__((ext_vector_type(16))) float f32x16;
typedef __attribute__((ext_vector_type(2))) __fp16 fp16x2;
typedef unsigned int u32;
typedef unsigned long long u64;

#define C1 0.180336880111121f    // 0.125 * log2(e)
#define CM (-14426.9504088896f)  // -10000 * log2(e)  (fallback kernel only)

static __device__ __forceinline__ unsigned short f2bf(float f) {
  union { float f; unsigned u; } x; x.f = f;
  return (unsigned short)((x.u + 0x8000u) >> 16);
}
static __device__ __forceinline__ unsigned packbf(float lo, float hi) {
  union { float f; unsigned u; } a, b; a.f = lo; b.f = hi;
  return ((a.u + 0x8000u) >> 16) | ((b.u + 0x8000u) & 0xffff0000u);
}
static __device__ __forceinline__ f32x16 zero16() {
  f32x16 z;
#pragma unroll
  for (int i = 0; i < 16; ++i) z[i] = 0.f;
  return z;
}
static __device__ __forceinline__ void dma16(const u32* g, u32* l) {
  __builtin_amdgcn_global_load_lds(
      (const __attribute__((address_space(1))) u32*)g,
      (__attribute__((address_space(3))) u32*)l, 16, 0, 0);
}
static __device__ __forceinline__ unsigned pkh(float lo, float hi) {
  union { fp16x2 h; unsigned u; } x;
  x.h = __builtin_amdgcn_cvt_pkrtz(lo, hi);
  return x.u;
}

// ---- pre-pass: K -> bf16 tile images; V -> f16 transposed+swizzled ----
__global__ __launch_bounds__(256) void prep_kv(
    const float* __restrict__ k, const float* __restrict__ v,
    unsigned short* __restrict__ kws, unsigned short* __restrict__ vws) {
  const int kt = blockIdx.x, bh = blockIdx.y;
  const int t = threadIdx.x;
  __shared__ unsigned short Vt[TILE_SHORTS];
  const size_t goff = (size_t)bh * (S_LEN * D_DIM) + (size_t)kt * 64 * D_DIM;
  const float4* kg = (const float4*)(k + goff);
  const float4* vg = (const float4*)(v + goff);
  unsigned short* kimg = kws + (size_t)(bh * N_KT + kt) * TILE_SHORTS;
#pragma unroll
  for (int j = 0; j < 4; ++j) {
    const int i = t + j * 256;
    const int row = i >> 4, c4 = i & 15;  // row = key, c4 = d-group
    const float4 x = kg[i];
    ushort4 w;
    w.x = f2bf(x.x); w.y = f2bf(x.y); w.z = f2bf(x.z); w.w = f2bf(x.w);
    *(ushort4*)&kimg[row * LDK + c4 * 4] = w;
    const float4 y = vg[i];
    const int swc = 8 * (((row >> 3) + c4) & 7) + (row & 7);
    const unsigned p01 = pkh(y.x, y.y);
    const unsigned p23 = pkh(y.z, y.w);
    Vt[(4 * c4 + 0) * LDV + swc] = (unsigned short)(p01 & 0xffff);
    Vt[(4 * c4 + 1) * LDV + swc] = (unsigned short)(p01 >> 16);
    Vt[(4 * c4 + 2) * LDV + swc] = (unsigned short)(p23 & 0xffff);
    Vt[(4 * c4 + 3) * LDV + swc] = (unsigned short)(p23 >> 16);
  }
  __syncthreads();
  uint4* vimg = (uint4*)(vws + (size_t)(bh * N_KT + kt) * TILE_SHORTS);
  const uint4* lv = (const uint4*)Vt;
  for (int i = t; i < TILE_BYTES / 16; i += 256) vimg[i] = lv[i];
}

// ---- pre-pass: mask -> u32 AND-words in per-lane pair layout ----
// word for (row, hl, kt, p): p = kb*8 + g*2 + h covers keys
// j = 32*kb + 8*g + 4*hl + 2*h + {0,1}; half = mask==0 ? 0xFFFF : 0.
__global__ __launch_bounds__(256) void prep_mask(
    const int* __restrict__ mask, u32* __restrict__ mw) {
  const int wid = blockIdx.x * 4 + (threadIdx.x >> 6);  // row*32 + kt
  const int lane = threadIdx.x & 63;
  const int row = wid >> 5, kt = wid & 31;
  const int mv = mask[(size_t)row * S_LEN + kt * 64 + lane];
  const u64 b = __ballot(mv != 0);
  if (lane < 32) {
    const int hl = lane >> 4, p = lane & 15;
    const int kb = p >> 3, g = (p >> 1) & 3, h = p & 1;
    const int j0 = 32 * kb + 8 * g + 4 * hl + 2 * h;
    u32 w = 0;
    if (!((b >> j0) & 1)) w |= 0x0000FFFFu;
    if (!((b >> (j0 + 1)) & 1)) w |= 0xFFFF0000u;
    mw[((size_t)(row * 2 + hl) * N_KT + kt) * 16 + p] = w;
  }
}

// ---- main: flash attention, DMA-staged tiles, lean softmax ----
__global__ __launch_bounds__(128, 2) void attn_fwd(
    const float* __restrict__ q, const unsigned short* __restrict__ kws,
    const unsigned short* __restrict__ vws, const u32* __restrict__ mw,
    float* __restrict__ out) {
  const int qt = blockIdx.x;  // 0..31 (64 q rows per block)
  const int bh = blockIdx.y;  // 0..31
  const size_t hoff = (size_t)bh * (S_LEN * D_DIM);

  __shared__ unsigned short Ks[2][TILE_SHORTS];
  __shared__ unsigned short Vt[2][TILE_SHORTS];

  const int t = threadIdx.x;
  const int wave = t >> 6;
  const int lane = t & 63;
  const int col = lane & 31;
  const int hl = lane >> 5;
  const int sw = col >> 2;

  const int qg = qt * 64 + wave * 32 + col;  // this lane's q row within head

  // Q^T B-fragments from global, PRE-SCALED by C1: B[k=d][n=q]
  bf16x8 bQ[4];
  {
    const float* qrow = q + hoff + (size_t)qg * D_DIM;
#pragma unroll
    for (int ks = 0; ks < 4; ++ks) {
      const float4 x0 = *(const float4*)(qrow + ks * 16 + hl * 8);
      const float4 x1 = *(const float4*)(qrow + ks * 16 + hl * 8 + 4);
      union { bf16x8 v; unsigned d[4]; } u;
      u.d[0] = packbf(x0.x * C1, x0.y * C1);
      u.d[1] = packbf(x0.z * C1, x0.w * C1);
      u.d[2] = packbf(x1.x * C1, x1.y * C1);
      u.d[3] = packbf(x1.z * C1, x1.w * C1);
      bQ[ks] = u.v;
    }
  }

  // ones A-fragment (f16 1.0) for the l row-sum MFMA
  bf16x8 onesA;
  {
    union { bf16x8 v; unsigned d[4]; } u;
    u.d[0] = u.d[1] = u.d[2] = u.d[3] = 0x3C003C00u;
    onesA = u.v;
  }

  const unsigned short* kbase = kws + (size_t)bh * N_KT * TILE_SHORTS;
  const unsigned short* vbase = vws + (size_t)bh * N_KT * TILE_SHORTS;

  f32x16 oT0 = zero16(), oT1 = zero16(), oL = zero16();
  const uint4* mrow = (const uint4*)(mw + (size_t)(qg * 2 + hl) * N_KT * 16);

  // stage tile 0 into buf 0 (wave 0: K, wave 1: V)
  {
    const u32* g = (const u32*)((wave == 0 ? kbase : vbase));
    u32* l = wave == 0 ? (u32*)&Ks[0][0] : (u32*)&Vt[0][0];
#pragma unroll
    for (int i = 0; i < 9; ++i) dma16(g + i * 256 + lane * 4, l + i * 256);
  }

  for (int kt = 0; kt < N_KT; ++kt) {
    __syncthreads();  // drains DMA for tile kt; orders buffer reuse
    if (kt + 1 < N_KT) {
      const u32* g = (const u32*)((wave == 0 ? kbase : vbase) +
                                  (size_t)(kt + 1) * TILE_SHORTS);
      u32* l = wave == 0 ? (u32*)&Ks[(kt + 1) & 1][0]
                         : (u32*)&Vt[(kt + 1) & 1][0];
#pragma unroll
      for (int i = 0; i < 9; ++i) dma16(g + i * 256 + lane * 4, l + i * 256);
    }
    // mask AND-words for this tile (64 B, contiguous)
    uint4 mq0 = mrow[kt * 4 + 0], mq1 = mrow[kt * 4 + 1];
    uint4 mq2 = mrow[kt * 4 + 2], mq3 = mrow[kt * 4 + 3];
    const u32 mwv[16] = {mq0.x, mq0.y, mq0.z, mq0.w, mq1.x, mq1.y, mq1.z, mq1.w,
                         mq2.x, mq2.y, mq2.z, mq2.w, mq3.x, mq3.y, mq3.z, mq3.w};
    const unsigned short* Ksb = Ks[kt & 1];
    const unsigned short* Vtb = Vt[kt & 1];

    // S^T = K Q^T : 2 key-blocks x 4 k-steps (scores pre-scaled via Q)
    f32x16 sT0 = zero16(), sT1 = zero16();
#pragma unroll
    for (int ks = 0; ks < 4; ++ks) {
      const bf16x8 aK0 = *(const bf16x8*)&Ksb[col * LDK + ks * 16 + hl * 8];
      const bf16x8 aK1 = *(const bf16x8*)&Ksb[(32 + col) * LDK + ks * 16 + hl * 8];
      sT0 = __builtin_amdgcn_mfma_f32_32x32x16_bf16(aK0, bQ[ks], sT0, 0, 0, 0);
      sT1 = __builtin_amdgcn_mfma_f32_32x32x16_bf16(aK1, bQ[ks], sT1, 0, 0, 0);
    }

    // p = exp2(s), pack f16 pairs (pkrtz), mask with AND-words
    unsigned pw[16];
#pragma unroll
    for (int kb = 0; kb < 2; ++kb) {
      const f32x16 sT = kb ? sT1 : sT0;
#pragma unroll
      for (int g = 0; g < 4; ++g) {
        const float e0 = __builtin_amdgcn_exp2f(sT[g * 4 + 0]);
        const float e1 = __builtin_amdgcn_exp2f(sT[g * 4 + 1]);
        const float e2 = __builtin_amdgcn_exp2f(sT[g * 4 + 2]);
        const float e3 = __builtin_amdgcn_exp2f(sT[g * 4 + 3]);
        pw[kb * 8 + g * 2 + 0] = pkh(e0, e1) & mwv[kb * 8 + g * 2 + 0];
        pw[kb * 8 + g * 2 + 1] = pkh(e2, e3) & mwv[kb * 8 + g * 2 + 1];
      }
    }

    // O^T += Vt * P^T ; l += ones * P^T (exact row-sum of masked P)
#pragma unroll
    for (int ks = 0; ks < 4; ++ks) {
      const int kb = ks >> 1, h = ks & 1;
      const unsigned d0 = pw[kb * 8 + 4 * h + 0], d1 = pw[kb * 8 + 4 * h + 1];
      const unsigned d2 = pw[kb * 8 + 4 * h + 2], d3 = pw[kb * 8 + 4 * h + 3];
      const unsigned s0 = hl ? d0 : d2;
      const unsigned s1 = hl ? d1 : d3;
      const unsigned r0 = (unsigned)__shfl_xor((int)s0, 32);
      const unsigned r1 = (unsigned)__shfl_xor((int)s1, 32);
      union { bf16x8 v; unsigned d[4]; } pf;
      pf.d[0] = hl ? r0 : d0;
      pf.d[1] = hl ? r1 : d1;
      pf.d[2] = hl ? d2 : r0;
      pf.d[3] = hl ? d3 : r1;
      const int cpr = 8 * (((2 * ks + hl) + sw) & 7);
      const bf16x8 aV0 = *(const bf16x8*)&Vtb[col * LDV + cpr];
      const bf16x8 aV1 = *(const bf16x8*)&Vtb[(32 + col) * LDV + cpr];
      oT0 = __builtin_amdgcn_mfma_f32_32x32x16_f16(aV0, pf.v, oT0, 0, 0, 0);
      oT1 = __builtin_amdgcn_mfma_f32_32x32x16_f16(aV1, pf.v, oT1, 0, 0, 0);
      oL = __builtin_amdgcn_mfma_f32_32x32x16_f16(onesA, pf.v, oL, 0, 0, 0);
    }
  }

  const float inv = 1.0f / oL[0];  // every C row of ones*P^T equals l(q=col)
  float* orow = out + hoff + (size_t)qg * D_DIM;
#pragma unroll
  for (int rg = 0; rg < 4; ++rg) {
    float4 w0, w1;
    w0.x = oT0[rg * 4 + 0] * inv; w0.y = oT0[rg * 4 + 1] * inv;
    w0.z = oT0[rg * 4 + 2] * inv; w0.w = oT0[rg * 4 + 3] * inv;
    w1.x = oT1[rg * 4 + 0] * inv; w1.y = oT1[rg * 4 + 1] * inv;
    w1.z = oT1[rg * 4 + 2] * inv; w1.w = oT1[rg * 4 + 3] * inv;
    *(float4*)(orow + 8 * rg + 4 * hl) = w0;
    *(float4*)(orow + 32 + 8 * rg + 4 * hl) = w1;
  }
}

// ---- fallback (round-4 kernel, self-staging) if ws is too small ----
__global__ __launch_bounds__(256, 2) void attn_fwd_self(
    const float* __restrict__ q, const float* __restrict__ k,
    const float* __restrict__ v, const int* __restrict__ mask,
    float* __restrict__ out) {
  const int qt = blockIdx.x;
  const int bh = blockIdx.y;
  const size_t hoff = (size_t)bh * (S_LEN * D_DIM);
  __shared__ unsigned short Ks[64 * LDK];
  __shared__ unsigned short Vt[64 * LDV];
  const int t = threadIdx.x;
  const int wave = t >> 6;
  const int lane = t & 63;
  const int col = lane & 31;
  const int hl = lane >> 5;
  const int sw = col >> 2;
  const int qg = qt * 128 + wave * 32 + col;
  bf16x8 bQ[4];
  {
    const float* qrow = q + hoff + (size_t)qg * D_DIM;
#pragma unroll
    for (int ks = 0; ks < 4; ++ks) {
      const float4 x0 = *(const float4*)(qrow + ks * 16 + hl * 8);
      const float4 x1 = *(const float4*)(qrow + ks * 16 + hl * 8 + 4);
      union { bf16x8 v; unsigned d[4]; } u;
      u.d[0] = packbf(x0.x, x0.y);
      u.d[1] = packbf(x0.z, x0.w);
      u.d[2] = packbf(x1.x, x1.y);
      u.d[3] = packbf(x1.z, x1.w);
      bQ[ks] = u.v;
    }
  }
  float4 pk[4], pv[4];
  {
    const float4* kg = (const float4*)(k + hoff);
    const float4* vg = (const float4*)(v + hoff);
#pragma unroll
    for (int j = 0; j < 4; ++j) { pk[j] = kg[t + j * 256]; pv[j] = vg[t + j * 256]; }
  }
  f32x16 oT0 = zero16(), oT1 = zero16();
  float lacc = 0.f;
  const int* mrow = mask + (size_t)qg * S_LEN;
  for (int kt = 0; kt < N_KT; ++kt) {
    __syncthreads();
#pragma unroll
    for (int j = 0; j < 4; ++j) {
      const int i = t + j * 256;
      const int row = i >> 4, c4 = i & 15;
      ushort4 w;
      w.x = f2bf(pk[j].x); w.y = f2bf(pk[j].y);
      w.z = f2bf(pk[j].z); w.w = f2bf(pk[j].w);
      *(ushort4*)&Ks[row * LDK + c4 * 4] = w;
      const int swc = 8 * (((row >> 3) + c4) & 7) + (row & 7);
      Vt[(4 * c4 + 0) * LDV + swc] = f2bf(pv[j].x);
      Vt[(4 * c4 + 1) * LDV + swc] = f2bf(pv[j].y);
      Vt[(4 * c4 + 2) * LDV + swc] = f2bf(pv[j].z);
      Vt[(4 * c4 + 3) * LDV + swc] = f2bf(pv[j].w);
    }
    __syncthreads();
    if (kt + 1 < N_KT) {
      const float4* kg = (const float4*)(k + hoff + (size_t)(kt + 1) * 64 * D_DIM);
      const float4* vg = (const float4*)(v + hoff + (size_t)(kt + 1) * 64 * D_DIM);
#pragma unroll
      for (int j = 0; j < 4; ++j) { pk[j] = kg[t + j * 256]; pv[j] = vg[t + j * 256]; }
    }
    int4 mq[2][4];
#pragma unroll
    for (int kb = 0; kb < 2; ++kb)
#pragma unroll
      for (int g = 0; g < 4; ++g)
        mq[kb][g] = *(const int4*)(mrow + kt * 64 + kb * 32 + g * 8 + hl * 4);
    f32x16 sT0 = zero16(), sT1 = zero16();
#pragma unroll
    for (int ks = 0; ks < 4; ++ks) {
      const bf16x8 aK0 = *(const bf16x8*)&Ks[col * LDK + ks * 16 + hl * 8];
      const bf16x8 aK1 = *(const bf16x8*)&Ks[(32 + col) * LDK + ks * 16 + hl * 8];
      sT0 = __builtin_amdgcn_mfma_f32_32x32x16_bf16(aK0, bQ[ks], sT0, 0, 0, 0);
      sT1 = __builtin_amdgcn_mfma_f32_32x32x16_bf16(aK1, bQ[ks], sT1, 0, 0, 0);
    }
    unsigned pw[2][8];
#pragma unroll
    for (int kb = 0; kb < 2; ++kb) {
      const f32x16 sT = kb ? sT1 : sT0;
      float e[16];
#pragma unroll
      for (int g = 0; g < 4; ++g) {
        const int4 mv = mq[kb][g];
        const int* mvp = &mv.x;
#pragma unroll
        for (int r3 = 0; r3 < 4; ++r3) {
          const int reg = g * 4 + r3;
          const float bias = mvp[r3] ? CM : 0.0f;
          const float ev = __builtin_amdgcn_exp2f(fmaf(sT[reg], C1, bias));
          e[reg] = ev;
          lacc += ev;
        }
        pw[kb][g * 2 + 0] = packbf(e[g * 4 + 0], e[g * 4 + 1]);
        pw[kb][g * 2 + 1] = packbf(e[g * 4 + 2], e[g * 4 + 3]);
      }
    }
#pragma unroll
    for (int ks = 0; ks < 4; ++ks) {
      const int kb = ks >> 1, h = ks & 1;
      const unsigned d0 = pw[kb][4 * h + 0], d1 = pw[kb][4 * h + 1];
      const unsigned d2 = pw[kb][4 * h + 2], d3 = pw[kb][4 * h + 3];
      const unsigned s0 = hl ? d0 : d2;
      const unsigned s1 = hl ? d1 : d3;
      const unsigned r0 = (unsigned)__shfl_xor((int)s0, 32);
      const unsigned r1 = (unsigned)__shfl_xor((int)s1, 32);
      union { bf16x8 v; unsigned d[4]; } pf;
      pf.d[0] = hl ? r0 : d0;
      pf.d[1] = hl ? r1 : d1;
      pf.d[2] = hl ? d2 : r0;
      pf.d[3] = hl ? d3 : r1;
      const int cpr = 8 * (((2 * ks + hl) + sw) & 7);
      const bf16x8 aV0 = *(const bf16x8*)&Vt[col * LDV + cpr];
      const bf16x8 aV1 = *(const bf16x8*)&Vt[(32 + col) * LDV + cpr];
      oT0 = __builtin_amdgcn_mfma_f32_32x32x16_bf16(aV0, pf.v, oT0, 0, 0, 0);
      oT1 = __builtin_amdgcn_mfma_f32_32x32x16_bf16(aV1, pf.v, oT1, 0, 0, 0);
    }
  }
  const float ltot = lacc + __shfl_xor(lacc, 32);
  const float inv = 1.0f / ltot;
  float* orow = out + hoff + (size_t)qg * D_DIM;
#pragma unroll
  for (int rg = 0; rg < 4; ++rg) {
    float4 w0, w1;
    w0.x = oT0[rg * 4 + 0] * inv; w0.y = oT0[rg * 4 + 1] * inv;
    w0.z = oT0[rg * 4 + 2] * inv; w0.w = oT0[rg * 4 + 3] * inv;
    w1.x = oT1[rg * 4 + 0] * inv; w1.y = oT1[rg * 4 + 1] * inv;
    w1.z = oT1[rg * 4 + 2] * inv; w1.w = oT1[rg * 4 + 3] * inv;
    *(float4*)(orow + 8 * rg + 4 * hl) = w0;
    *(float4*)(orow + 32 + 8 * rg + 4 * hl) = w1;
  }
}

extern "C" void kernel_launch(void* const* d_in, const int* in_sizes, int n_in,
                              void* d_out, int out_size, void* d_ws, size_t ws_size,
                              hipStream_t stream) {
  const float* q = (const float*)d_in[0];
  const float* k = (const float*)d_in[1];
  const float* v = (const float*)d_in[2];
  const int* mask = (const int*)d_in[3];
  float* out = (float*)d_out;

  const size_t img_elems = (size_t)NBH * N_KT * TILE_SHORTS;      // shorts
  const size_t mw_words = (size_t)S_LEN * 2 * N_KT * 16;          // u32 count
  const size_t need = img_elems * 2 * sizeof(unsigned short) + mw_words * 4;

  if (ws_size >= need) {
    unsigned short* kws = (unsigned short*)d_ws;
    unsigned short* vws = kws + img_elems;
    u32* mwp = (u32*)(vws + img_elems);
    prep_kv<<<dim3(N_KT, NBH), dim3(256), 0, stream>>>(k, v, kws, vws);
    prep_mask<<<dim3((S_LEN * N_KT) / 4), dim3(256), 0, stream>>>(mask, mwp);
    attn_fwd<<<dim3(S_LEN / 64, NBH), dim3(128), 0, stream>>>(q, kws, vws, mwp, out);
  } else {
    attn_fwd_self<<<dim3(S_LEN / 128, NBH), dim3(256), 0, stream>>>(q, k, v, mask, out);
  }
}